// Round 1
// baseline (460.590 us; speedup 1.0000x reference)
//
#include <hip/hip_runtime.h>

#define IN_C   16
#define OUT_C  16
#define EDGE_DIM 8
#define HID    32

// out[n][o] = bias[o] + sum_i x[n][i] * root[i][o]
__global__ __launch_bounds__(256) void nnconv_init_out(
    const float* __restrict__ x, const float* __restrict__ root,
    const float* __restrict__ bias, float* __restrict__ out, int n_nodes)
{
    int t = blockIdx.x * blockDim.x + threadIdx.x; // t = n*16 + o
    if (t >= n_nodes * OUT_C) return;
    int n = t >> 4, o = t & 15;
    float acc = bias[o];
    #pragma unroll
    for (int i = 0; i < IN_C; ++i)
        acc = fmaf(x[n * IN_C + i], root[i * OUT_C + o], acc);
    out[t] = acc;
}

// one thread per edge: MLP -> per-edge 16x16 weight -> msg -> atomic scatter
__global__ __launch_bounds__(256) void nnconv_edge(
    const float* __restrict__ x, const int* __restrict__ edge_index,
    const float* __restrict__ pseudo,
    const float* __restrict__ W1, const float* __restrict__ b1,
    const float* __restrict__ W2, const float* __restrict__ b2,
    float* __restrict__ out, int n_edges)
{
    int e = blockIdx.x * blockDim.x + threadIdx.x;
    if (e >= n_edges) return;
    int row = edge_index[e];
    int col = edge_index[n_edges + e];

    // load pseudo[e][0:8] (coalesced float4 x2)
    float p[EDGE_DIM];
    const float4* pp = reinterpret_cast<const float4*>(pseudo + (size_t)e * EDGE_DIM);
    float4 p0 = pp[0], p1 = pp[1];
    p[0]=p0.x; p[1]=p0.y; p[2]=p0.z; p[3]=p0.w;
    p[4]=p1.x; p[5]=p1.y; p[6]=p1.z; p[7]=p1.w;

    // h = relu(p @ W1 + b1)   (W1/b1 indices wave-uniform -> scalar loads)
    float h[HID];
    #pragma unroll
    for (int j = 0; j < HID; ++j) {
        float a = b1[j];
        #pragma unroll
        for (int k = 0; k < EDGE_DIM; ++k)
            a = fmaf(p[k], W1[k * HID + j], a);
        h[j] = a > 0.f ? a : 0.f;
    }

    // gather x[col] (16 floats, L2-resident)
    float xg[IN_C];
    const float4* xp = reinterpret_cast<const float4*>(x + (size_t)col * IN_C);
    #pragma unroll
    for (int q = 0; q < 4; ++q) {
        float4 v = xp[q];
        xg[q*4+0]=v.x; xg[q*4+1]=v.y; xg[q*4+2]=v.z; xg[q*4+3]=v.w;
    }

    float msg[OUT_C];
    #pragma unroll
    for (int o = 0; o < OUT_C; ++o) msg[o] = 0.f;

    // msg[o] = sum_i xg[i] * ( b2[i*16+o] + sum_j h[j]*W2[j][i*16+o] )
    for (int i = 0; i < IN_C; ++i) {   // rolled: keeps code size sane
        float w[OUT_C];
        const float* b2r = b2 + i * OUT_C;
        #pragma unroll
        for (int o = 0; o < OUT_C; ++o) w[o] = b2r[o];
        #pragma unroll
        for (int j = 0; j < HID; ++j) {
            float hj = h[j];
            const float* wr = W2 + j * (IN_C * OUT_C) + i * OUT_C; // wave-uniform
            #pragma unroll
            for (int o = 0; o < OUT_C; ++o)
                w[o] = fmaf(hj, wr[o], w[o]);
        }
        float xi = xg[i];
        #pragma unroll
        for (int o = 0; o < OUT_C; ++o)
            msg[o] = fmaf(xi, w[o], msg[o]);
    }

    float* op = out + (size_t)row * OUT_C;
    #pragma unroll
    for (int o = 0; o < OUT_C; ++o)
        atomicAdd(op + o, msg[o]);
}

extern "C" void kernel_launch(void* const* d_in, const int* in_sizes, int n_in,
                              void* d_out, int out_size, void* d_ws, size_t ws_size,
                              hipStream_t stream) {
    const float* x        = (const float*)d_in[0];
    const int*   eidx     = (const int*)  d_in[1];
    const float* pseudo   = (const float*)d_in[2];
    const float* W1       = (const float*)d_in[3];
    const float* b1       = (const float*)d_in[4];
    const float* W2       = (const float*)d_in[5];
    const float* b2       = (const float*)d_in[6];
    const float* root     = (const float*)d_in[7];
    const float* bias     = (const float*)d_in[8];
    float* out = (float*)d_out;

    int n_nodes = in_sizes[0] / IN_C;
    int n_edges = in_sizes[1] / 2;

    int init_threads = n_nodes * OUT_C;
    nnconv_init_out<<<(init_threads + 255) / 256, 256, 0, stream>>>(
        x, root, bias, out, n_nodes);

    nnconv_edge<<<(n_edges + 255) / 256, 256, 0, stream>>>(
        x, eidx, pseudo, W1, b1, W2, b2, out, n_edges);
}

// Round 2
// 192.904 us; speedup vs baseline: 2.3877x; 2.3877x over previous
//
#include <hip/hip_runtime.h>

#define IN_C   16
#define OUT_C  16
#define EDGE_DIM 8
#define HID    32

// out[n][o] = bias[o] + sum_i x[n][i] * root[i][o]
__global__ __launch_bounds__(256) void nnconv_init_out(
    const float* __restrict__ x, const float* __restrict__ root,
    const float* __restrict__ bias, float* __restrict__ out, int n_nodes)
{
    int t = blockIdx.x * blockDim.x + threadIdx.x; // t = n*16 + o
    if (t >= n_nodes * OUT_C) return;
    int n = t >> 4, o = t & 15;
    float acc = bias[o];
    #pragma unroll
    for (int i = 0; i < IN_C; ++i)
        acc = fmaf(x[n * IN_C + i], root[i * OUT_C + o], acc);
    out[t] = acc;
}

__global__ __launch_bounds__(256) void nnconv_zero(int* cnt, int* cursor, int n)
{
    int t = blockIdx.x * blockDim.x + threadIdx.x;
    for (int i = t; i < 2 * n; i += gridDim.x * blockDim.x) {
        if (i < n) cnt[i] = 0;
        else cursor[i - n] = 0;
    }
}

__global__ __launch_bounds__(256) void nnconv_count(
    const int* __restrict__ edge_index, int* __restrict__ cnt, int n_edges)
{
    int e = blockIdx.x * blockDim.x + threadIdx.x;
    if (e >= n_edges) return;
    atomicAdd(&cnt[edge_index[e]], 1);
}

// single-block exclusive scan of cnt[n] -> base[n]
__global__ __launch_bounds__(256) void nnconv_scan(
    const int* __restrict__ cnt, int* __restrict__ base, int n)
{
    __shared__ int sums[256];
    int t = threadIdx.x;
    int chunk = (n + 255) >> 8;
    int lo = t * chunk, hi = lo + chunk; if (hi > n) hi = n; if (lo > n) lo = n;
    int s = 0;
    for (int i = lo; i < hi; ++i) s += cnt[i];
    sums[t] = s;
    __syncthreads();
    for (int off = 1; off < 256; off <<= 1) {
        int x = (t >= off) ? sums[t - off] : 0;
        __syncthreads();
        sums[t] += x;
        __syncthreads();
    }
    int run = sums[t] - s; // exclusive prefix of this thread's chunk
    for (int i = lo; i < hi; ++i) { base[i] = run; run += cnt[i]; }
}

// one thread per edge: MLP -> per-edge 16x16 weight -> msg -> store at sorted slot
__global__ __launch_bounds__(256) void nnconv_edge_sorted(
    const float* __restrict__ x, const int* __restrict__ edge_index,
    const float* __restrict__ pseudo,
    const float* __restrict__ W1, const float* __restrict__ b1,
    const float* __restrict__ W2, const float* __restrict__ b2,
    const int* __restrict__ base, int* __restrict__ cursor,
    float* __restrict__ msg, int n_edges)
{
    int e = blockIdx.x * blockDim.x + threadIdx.x;
    if (e >= n_edges) return;
    int row = edge_index[e];
    int col = edge_index[n_edges + e];

    float p[EDGE_DIM];
    const float4* pp = reinterpret_cast<const float4*>(pseudo + (size_t)e * EDGE_DIM);
    float4 p0 = pp[0], p1 = pp[1];
    p[0]=p0.x; p[1]=p0.y; p[2]=p0.z; p[3]=p0.w;
    p[4]=p1.x; p[5]=p1.y; p[6]=p1.z; p[7]=p1.w;

    float h[HID];
    #pragma unroll
    for (int j = 0; j < HID; ++j) {
        float a = b1[j];
        #pragma unroll
        for (int k = 0; k < EDGE_DIM; ++k)
            a = fmaf(p[k], W1[k * HID + j], a);
        h[j] = a > 0.f ? a : 0.f;
    }

    float xg[IN_C];
    const float4* xp = reinterpret_cast<const float4*>(x + (size_t)col * IN_C);
    #pragma unroll
    for (int q = 0; q < 4; ++q) {
        float4 v = xp[q];
        xg[q*4+0]=v.x; xg[q*4+1]=v.y; xg[q*4+2]=v.z; xg[q*4+3]=v.w;
    }

    float m[OUT_C];
    #pragma unroll
    for (int o = 0; o < OUT_C; ++o) m[o] = 0.f;

    for (int i = 0; i < IN_C; ++i) {
        float w[OUT_C];
        const float* b2r = b2 + i * OUT_C;
        #pragma unroll
        for (int o = 0; o < OUT_C; ++o) w[o] = b2r[o];
        #pragma unroll
        for (int j = 0; j < HID; ++j) {
            float hj = h[j];
            const float* wr = W2 + j * (IN_C * OUT_C) + i * OUT_C; // wave-uniform
            #pragma unroll
            for (int o = 0; o < OUT_C; ++o)
                w[o] = fmaf(hj, wr[o], w[o]);
        }
        float xi = xg[i];
        #pragma unroll
        for (int o = 0; o < OUT_C; ++o)
            m[o] = fmaf(xi, w[o], m[o]);
    }

    int slot = base[row] + atomicAdd(&cursor[row], 1);
    float4* mp = reinterpret_cast<float4*>(msg + (size_t)slot * OUT_C);
    mp[0] = make_float4(m[0], m[1], m[2], m[3]);
    mp[1] = make_float4(m[4], m[5], m[6], m[7]);
    mp[2] = make_float4(m[8], m[9], m[10], m[11]);
    mp[3] = make_float4(m[12], m[13], m[14], m[15]);
}

// wave per node: sum msg rows in [base[n], base[n]+cnt[n]), add to out
__global__ __launch_bounds__(256) void nnconv_gather(
    const float* __restrict__ msg, const int* __restrict__ base,
    const int* __restrict__ cnt, float* __restrict__ out, int n_nodes)
{
    int wave = threadIdx.x >> 6;
    int lane = threadIdx.x & 63;
    int n = blockIdx.x * 4 + wave;
    if (n >= n_nodes) return;
    int group = lane >> 4;  // 0..3
    int o = lane & 15;
    int s = base[n];
    int e = s + cnt[n];
    float acc = 0.f;
    for (int k = s + group; k < e; k += 4)
        acc += msg[(size_t)k * OUT_C + o];
    acc += __shfl_xor(acc, 16, 64);
    acc += __shfl_xor(acc, 32, 64);
    if (group == 0) {
        int idx = n * OUT_C + o;
        out[idx] = out[idx] + acc;
    }
}

// fallback (round-1 style) if ws too small
__global__ __launch_bounds__(256) void nnconv_edge_atomic(
    const float* __restrict__ x, const int* __restrict__ edge_index,
    const float* __restrict__ pseudo,
    const float* __restrict__ W1, const float* __restrict__ b1,
    const float* __restrict__ W2, const float* __restrict__ b2,
    float* __restrict__ out, int n_edges)
{
    int e = blockIdx.x * blockDim.x + threadIdx.x;
    if (e >= n_edges) return;
    int row = edge_index[e];
    int col = edge_index[n_edges + e];
    float p[EDGE_DIM];
    const float4* pp = reinterpret_cast<const float4*>(pseudo + (size_t)e * EDGE_DIM);
    float4 p0 = pp[0], p1 = pp[1];
    p[0]=p0.x; p[1]=p0.y; p[2]=p0.z; p[3]=p0.w;
    p[4]=p1.x; p[5]=p1.y; p[6]=p1.z; p[7]=p1.w;
    float h[HID];
    #pragma unroll
    for (int j = 0; j < HID; ++j) {
        float a = b1[j];
        #pragma unroll
        for (int k = 0; k < EDGE_DIM; ++k)
            a = fmaf(p[k], W1[k * HID + j], a);
        h[j] = a > 0.f ? a : 0.f;
    }
    float xg[IN_C];
    const float4* xp = reinterpret_cast<const float4*>(x + (size_t)col * IN_C);
    #pragma unroll
    for (int q = 0; q < 4; ++q) {
        float4 v = xp[q];
        xg[q*4+0]=v.x; xg[q*4+1]=v.y; xg[q*4+2]=v.z; xg[q*4+3]=v.w;
    }
    float m[OUT_C];
    #pragma unroll
    for (int o = 0; o < OUT_C; ++o) m[o] = 0.f;
    for (int i = 0; i < IN_C; ++i) {
        float w[OUT_C];
        const float* b2r = b2 + i * OUT_C;
        #pragma unroll
        for (int o = 0; o < OUT_C; ++o) w[o] = b2r[o];
        #pragma unroll
        for (int j = 0; j < HID; ++j) {
            float hj = h[j];
            const float* wr = W2 + j * (IN_C * OUT_C) + i * OUT_C;
            #pragma unroll
            for (int o = 0; o < OUT_C; ++o)
                w[o] = fmaf(hj, wr[o], w[o]);
        }
        float xi = xg[i];
        #pragma unroll
        for (int o = 0; o < OUT_C; ++o)
            m[o] = fmaf(xi, w[o], m[o]);
    }
    float* op = out + (size_t)row * OUT_C;
    #pragma unroll
    for (int o = 0; o < OUT_C; ++o)
        atomicAdd(op + o, m[o]);
}

extern "C" void kernel_launch(void* const* d_in, const int* in_sizes, int n_in,
                              void* d_out, int out_size, void* d_ws, size_t ws_size,
                              hipStream_t stream) {
    const float* x        = (const float*)d_in[0];
    const int*   eidx     = (const int*)  d_in[1];
    const float* pseudo   = (const float*)d_in[2];
    const float* W1       = (const float*)d_in[3];
    const float* b1       = (const float*)d_in[4];
    const float* W2       = (const float*)d_in[5];
    const float* b2       = (const float*)d_in[6];
    const float* root     = (const float*)d_in[7];
    const float* bias     = (const float*)d_in[8];
    float* out = (float*)d_out;

    int n_nodes = in_sizes[0] / IN_C;
    int n_edges = in_sizes[1] / 2;

    // ws layout: cnt[N] | base[N] | cursor[N] | (256B align) | msg[E*16]
    int* cnt    = (int*)d_ws;
    int* base   = cnt + n_nodes;
    int* cursor = base + n_nodes;
    size_t hdr = sizeof(int) * (size_t)(3 * n_nodes);
    hdr = (hdr + 255) & ~(size_t)255;
    float* msg = (float*)((char*)d_ws + hdr);
    size_t need = hdr + sizeof(float) * (size_t)n_edges * OUT_C;

    int init_threads = n_nodes * OUT_C;
    nnconv_init_out<<<(init_threads + 255) / 256, 256, 0, stream>>>(
        x, root, bias, out, n_nodes);

    if (ws_size < need) {
        nnconv_edge_atomic<<<(n_edges + 255) / 256, 256, 0, stream>>>(
            x, eidx, pseudo, W1, b1, W2, b2, out, n_edges);
        return;
    }

    nnconv_zero<<<64, 256, 0, stream>>>(cnt, cursor, n_nodes);
    nnconv_count<<<(n_edges + 255) / 256, 256, 0, stream>>>(eidx, cnt, n_edges);
    nnconv_scan<<<1, 256, 0, stream>>>(cnt, base, n_nodes);
    nnconv_edge_sorted<<<(n_edges + 255) / 256, 256, 0, stream>>>(
        x, eidx, pseudo, W1, b1, W2, b2, base, cursor, msg, n_edges);
    nnconv_gather<<<(n_nodes + 3) / 4, 256, 0, stream>>>(
        msg, base, cnt, out, n_nodes);
}